// Round 13
// baseline (414.177 us; speedup 1.0000x reference)
//
#include <hip/hip_runtime.h>
#include <math.h>

#define N_NODES 1024
#define BATCH   64
#define F_IN    128     // D_IN + UNITS (K of the projection GEMM)
#define UNITS   64
#define NUM_M   5
#define CAP     192     // ELL row capacity (max row degree ~55 for this seed)
#define NT1     640     // 5*128 output cols, gconv1
#define NT2     320     // 5*64  output cols, gconv2
#define DSTR    12      // diffusion LDS row stride (floats): empirically best (r9/r12)

typedef __attribute__((ext_vector_type(8))) short short8v;
typedef __attribute__((ext_vector_type(4))) float f32x4;

__device__ __forceinline__ unsigned short bf16_rne(float x) {
    unsigned u = __float_as_uint(x);
    return (unsigned short)((u + 0x7FFFu + ((u >> 16) & 1u)) >> 16);
}

// ---------------- degree count per row --------------------------------------
__global__ void degree_count(const float* __restrict__ L, int* __restrict__ dcnt) {
    int row  = blockIdx.x * 4 + (threadIdx.x >> 6);
    int lane = threadIdx.x & 63;
    const float* Lr = L + (size_t)row * N_NODES;
    int c = 0;
    for (int seg = lane; seg < N_NODES; seg += 64) c += (Lr[seg] != 0.0f);
    #pragma unroll
    for (int o = 1; o < 64; o <<= 1) c += __shfl_xor(c, o);
    if (lane == 0) dcnt[row] = c;
}

// ---------------- counting sort by degree (descending) ----------------------
__global__ void sort_perm(const int* __restrict__ dcnt, int* __restrict__ perm) {
    __shared__ int hist[CAP + 1];
    __shared__ int offs[CAP + 1];
    int tid = threadIdx.x;
    for (int i = tid; i <= CAP; i += 256) hist[i] = 0;
    __syncthreads();
    for (int r = tid; r < N_NODES; r += 256) {
        int c = dcnt[r]; if (c > CAP) c = CAP;
        atomicAdd(&hist[c], 1);
    }
    __syncthreads();
    if (tid == 0) {
        int s = 0;
        for (int c = CAP; c >= 0; --c) { offs[c] = s; s += hist[c]; }
    }
    __syncthreads();
    for (int r = tid; r < N_NODES; r += 256) {
        int c = dcnt[r]; if (c > CAP) c = CAP;
        int pos = atomicAdd(&offs[c], 1);
        perm[pos] = r;
    }
}

// ---------------- ELL build in sorted row order -----------------------------
__global__ void ell_build(const float* __restrict__ L, const int* __restrict__ perm,
                          int* __restrict__ scnt, float2* __restrict__ ell) {
    int p    = blockIdx.x * 4 + (threadIdx.x >> 6);
    int lane = threadIdx.x & 63;
    int row  = perm[p];
    const float* Lr = L + (size_t)row * N_NODES;
    int base = 0;
    for (int seg = 0; seg < N_NODES; seg += 64) {
        float v = Lr[seg + lane];
        bool nz = (v != 0.0f);
        unsigned long long bal = __ballot(nz);
        int off = __popcll(bal & ((1ull << lane) - 1ull));
        if (nz) {
            int idx = base + off;
            if (idx < CAP) ell[(size_t)idx * N_NODES + p] =
                               make_float2(__int_as_float(seg + lane), v);
        }
        base += __popcll(bal);
    }
    if (base > CAP) base = CAP;
    for (int idx = base + lane; idx < CAP; idx += 64)
        ell[(size_t)idx * N_NODES + p] = make_float2(__int_as_float(0), 0.0f);
    if (lane == 0) scnt[p] = (base + 3) & ~3;
}

// ---------------- W' prep: fold + bf16 hi/lo split + MFMA fragment order ----
__global__ void wprep_frag(const float* __restrict__ W, unsigned short* __restrict__ Wh,
                           unsigned short* __restrict__ Wl, int nout, int ntot) {
    int idx = blockIdx.x * blockDim.x + threadIdx.x;
    if (idx >= F_IN * ntot) return;
    int jg = idx % ntot, k = idx / ntot;
    int m = jg / nout, j = jg % nout;
    const float* Wk = W + (size_t)(k * NUM_M) * nout;
    float v;
    if (m == 0)      v = Wk[0 * nout + j] - Wk[3 * nout + j] - Wk[4 * nout + j];
    else if (m == 3) v = 2.0f * Wk[3 * nout + j];
    else if (m == 4) v = 2.0f * Wk[4 * nout + j];
    else             v = Wk[(size_t)m * nout + j];
    unsigned short h = bf16_rne(v);
    float hf = __uint_as_float((unsigned)h << 16);
    unsigned short lo = bf16_rne(v - hf);
    size_t fi = ((((size_t)(jg >> 4) * 4 + (k >> 5)) * 64) + ((k >> 3) & 3) * 16 + (jg & 15)) * 8 + (k & 7);
    Wh[fi] = h; Wl[fi] = lo;
}

// ---------------- MFMA projection v7: fp32 A loads, in-reg split, zero-LDS --
// P^T = W'^T @ xin^T (W frag as MFMA A-operand, X frag as B-operand).
template <int NCG, int RMUL>
__global__ __launch_bounds__(128, 3) void gemm_proj(
        const float* __restrict__ inp, const float* __restrict__ hx,
        const float* __restrict__ rh,
        const unsigned short* __restrict__ Wh, const unsigned short* __restrict__ Wl,
        float* __restrict__ P, int nrows, int row0) {
    const int tid = threadIdx.x;
    const int lane = tid & 63, w = tid >> 6;          // 2 waves/block
    const int l15 = lane & 15, l4 = lane >> 4;
    const int nbase = blockIdx.x * 64 + w * 32;

    short8v ah[2][4], al[2][4];                        // X frags, hoisted
    #pragma unroll
    for (int i = 0; i < 2; ++i)
        #pragma unroll
        for (int s = 0; s < 4; ++s) {
            int row_l = nbase + i * 16 + l15;
            int kg8 = s * 4 + l4;
            size_t g = (size_t)(row0 + row_l);
            float x[8];
            if (kg8 < 8) {
                *(float4*)&x[0] = *(const float4*)(inp + g * 64 + kg8 * 8);
                *(float4*)&x[4] = *(const float4*)(inp + g * 64 + kg8 * 8 + 4);
            } else if (RMUL) {
                const float* rp = rh + ((size_t)(kg8 - 8) * nrows + row_l) * 8;
                *(float4*)&x[0] = *(const float4*)(rp);
                *(float4*)&x[4] = *(const float4*)(rp + 4);
            } else {
                *(float4*)&x[0] = *(const float4*)(hx + g * 64 + (kg8 - 8) * 8);
                *(float4*)&x[4] = *(const float4*)(hx + g * 64 + (kg8 - 8) * 8 + 4);
            }
            #pragma unroll
            for (int e = 0; e < 8; ++e) {
                unsigned short h = bf16_rne(x[e]);
                ah[i][s][e] = (short)h;
                al[i][s][e] = (short)bf16_rne(x[e] - __uint_as_float((unsigned)h << 16));
            }
        }

    const int trow = l4 >> 1, toff = (l4 & 1) * 4;
    #pragma unroll 1
    for (int cg = 0; cg < NCG; ++cg) {
        f32x4 acc[2];
        acc[0] = (f32x4){0.f, 0.f, 0.f, 0.f};
        acc[1] = (f32x4){0.f, 0.f, 0.f, 0.f};
        #pragma unroll
        for (int s = 0; s < 4; ++s) {
            size_t o = (((size_t)cg * 4 + s) * 64 + lane) * 8;
            short8v bh = *(const short8v*)(Wh + o);
            short8v bl = *(const short8v*)(Wl + o);
            #pragma unroll
            for (int i = 0; i < 2; ++i) {
                acc[i] = __builtin_amdgcn_mfma_f32_16x16x32_bf16(bh, al[i][s], acc[i], 0, 0, 0);
                acc[i] = __builtin_amdgcn_mfma_f32_16x16x32_bf16(bl, ah[i][s], acc[i], 0, 0, 0);
                acc[i] = __builtin_amdgcn_mfma_f32_16x16x32_bf16(bh, ah[i][s], acc[i], 0, 0, 0);
            }
        }
        #pragma unroll
        for (int i = 0; i < 2; ++i) {
            float4 v = make_float4(acc[i][0], acc[i][1], acc[i][2], acc[i][3]);
            *(float4*)(P + ((size_t)(cg * 2 + trow) * nrows + (nbase + i * 16 + l15)) * 8 + toff) = v;
        }
    }
}

// ---------------- gather1: one sorted row, exact count, 4-deep ILP ----------
// Sequential j-order accumulation (bit-identical to reference row order).
__device__ __forceinline__ void gather1(
        const float2* __restrict__ ell, const float* __restrict__ ldsX,
        int p, int nn, float4& r0, float4& r1) {
    r0 = make_float4(0.f, 0.f, 0.f, 0.f);
    r1 = make_float4(0.f, 0.f, 0.f, 0.f);
    for (int j = 0; j < nn; j += 4) {        // nn is a multiple of 4; zero-fill to CAP
        float2 e0 = ell[(size_t)(j + 0) * N_NODES + p];
        float2 e1 = ell[(size_t)(j + 1) * N_NODES + p];
        float2 e2 = ell[(size_t)(j + 2) * N_NODES + p];
        float2 e3 = ell[(size_t)(j + 3) * N_NODES + p];
        const float* x0 = ldsX + (size_t)__float_as_int(e0.x) * DSTR;
        const float* x1 = ldsX + (size_t)__float_as_int(e1.x) * DSTR;
        const float* x2 = ldsX + (size_t)__float_as_int(e2.x) * DSTR;
        const float* x3 = ldsX + (size_t)__float_as_int(e3.x) * DSTR;
        float4 a0 = *(const float4*)x0, b0 = *(const float4*)(x0 + 4);
        float4 a1 = *(const float4*)x1, b1 = *(const float4*)(x1 + 4);
        float4 a2 = *(const float4*)x2, b2 = *(const float4*)(x2 + 4);
        float4 a3 = *(const float4*)x3, b3 = *(const float4*)(x3 + 4);
        r0.x += e0.y * a0.x; r0.y += e0.y * a0.y; r0.z += e0.y * a0.z; r0.w += e0.y * a0.w;
        r1.x += e0.y * b0.x; r1.y += e0.y * b0.y; r1.z += e0.y * b0.z; r1.w += e0.y * b0.w;
        r0.x += e1.y * a1.x; r0.y += e1.y * a1.y; r0.z += e1.y * a1.z; r0.w += e1.y * a1.w;
        r1.x += e1.y * b1.x; r1.y += e1.y * b1.y; r1.z += e1.y * b1.z; r1.w += e1.y * b1.w;
        r0.x += e2.y * a2.x; r0.y += e2.y * a2.y; r0.z += e2.y * a2.z; r0.w += e2.y * a2.w;
        r1.x += e2.y * b2.x; r1.y += e2.y * b2.y; r1.z += e2.y * b2.z; r1.w += e2.y * b2.w;
        r0.x += e3.y * a3.x; r0.y += e3.y * a3.y; r0.z += e3.y * a3.z; r0.w += e3.y * a3.w;
        r1.x += e3.y * b3.x; r1.y += e3.y * b3.y; r1.z += e3.y * b3.z; r1.w += e3.y * b3.w;
    }
}

// ---------------- diffuse2: 1024 threads, 1 sorted row/thread ---------------
// z=0: P1 += L0@P3 then P1 = L0@P1 ; z=1: P2 += L1@P4 then P2 = L1@P2.
// 16 waves/block, LDS 48 KB -> 2 blocks/CU (32 waves) if VGPR <= 64.
__global__ __launch_bounds__(1024, 2) void diffuse2(
        const int* __restrict__ scnt0, const float2* __restrict__ ell0, const int* __restrict__ perm0,
        const int* __restrict__ scnt1, const float2* __restrict__ ell1, const int* __restrict__ perm1,
        float* __restrict__ P, size_t sl, int nrows) {
    __shared__ float ldsX[N_NODES * DSTR];   // 48 KB
    const int tid = threadIdx.x;             // one sorted row per thread
    const int z = blockIdx.z;
    const int*    scnt = z ? scnt1 : scnt0;
    const float2* ell  = z ? ell1  : ell0;
    const int*    perm = z ? perm1 : perm0;
    const float*  src  = P + (size_t)(z ? 4 : 3) * sl;
    float*        dst  = P + (size_t)(z ? 2 : 1) * sl;   // also the add source
    const size_t base = ((size_t)blockIdx.x * nrows + (size_t)blockIdx.y * N_NODES) * 8;

    for (int v = tid; v < 2048; v += 1024) {
        float4 d = *(const float4*)(src + base + v * 4);
        *(float4*)(ldsX + (v >> 1) * DSTR + (v & 1) * 4) = d;
    }
    const int orow = perm[tid];
    const int nn   = scnt[tid];
    // prefetch add operand (HBM latency hides under pass-1 gather)
    const float* ap = dst + base + (size_t)orow * 8;
    float4 add0 = *(const float4*)ap, add1 = *(const float4*)(ap + 4);
    __syncthreads();

    float4 t0, t1;
    gather1(ell, ldsX, tid, nn, t0, t1);
    __syncthreads();                          // all pass-1 reads complete
    t0.x += add0.x; t0.y += add0.y; t0.z += add0.z; t0.w += add0.w;
    t1.x += add1.x; t1.y += add1.y; t1.z += add1.z; t1.w += add1.w;
    *(float4*)(ldsX + (size_t)orow * DSTR)     = t0;
    *(float4*)(ldsX + (size_t)orow * DSTR + 4) = t1;
    __syncthreads();
    float4 s0, s1;
    gather1(ell, ldsX, tid, nn, s0, s1);
    __syncthreads();
    *(float4*)(ldsX + (size_t)orow * DSTR)     = s0;
    *(float4*)(ldsX + (size_t)orow * DSTR + 4) = s1;
    __syncthreads();
    for (int v = tid; v < 2048; v += 1024)
        *(float4*)(dst + base + v * 4) = *(const float4*)(ldsX + (v >> 1) * DSTR + (v & 1) * 4);
}

// ---------------- combine1 (fused): u tiles + fp32 r*hx tiles ---------------
__global__ void combine1(const float* __restrict__ P, const float* __restrict__ b1,
                         const float* __restrict__ hx,
                         float* __restrict__ O1u, float* __restrict__ O1r,
                         int nrows, int row0) {
    int i  = blockIdx.x * 256 + threadIdx.x;
    int ft = blockIdx.y;
    size_t sl = (size_t)16 * nrows * 8;
    size_t o  = ((size_t)ft * nrows + i) * 8;
    float z[8];
    #pragma unroll
    for (int q = 0; q < 8; q += 4) {
        float4 p0 = *(const float4*)(P + o + q);
        float4 p1 = *(const float4*)(P + sl + o + q);
        float4 p2 = *(const float4*)(P + 2 * sl + o + q);
        float4 bb = *(const float4*)(b1 + ft * 8 + q);
        z[q + 0] = 1.f / (1.f + expf(-(p0.x + p1.x + p2.x + bb.x)));
        z[q + 1] = 1.f / (1.f + expf(-(p0.y + p1.y + p2.y + bb.y)));
        z[q + 2] = 1.f / (1.f + expf(-(p0.z + p1.z + p2.z + bb.z)));
        z[q + 3] = 1.f / (1.f + expf(-(p0.w + p1.w + p2.w + bb.w)));
    }
    if (ft >= 8) {
        size_t ou = ((size_t)(ft - 8) * nrows + i) * 8;
        *(float4*)(O1u + ou)     = make_float4(z[0], z[1], z[2], z[3]);
        *(float4*)(O1u + ou + 4) = make_float4(z[4], z[5], z[6], z[7]);
    } else {
        size_t g = (size_t)(row0 + i) * 64 + ft * 8;
        float4 h0 = *(const float4*)(hx + g), h1 = *(const float4*)(hx + g + 4);
        size_t orr = ((size_t)ft * nrows + i) * 8;
        *(float4*)(O1r + orr)     = make_float4(z[0] * h0.x, z[1] * h0.y, z[2] * h0.z, z[3] * h0.w);
        *(float4*)(O1r + orr + 4) = make_float4(z[4] * h1.x, z[5] * h1.y, z[6] * h1.z, z[7] * h1.w);
    }
}

// ---------------- combine2: out = u*hx + (1-u)*tanh(P0+S1+S2+b2) -----------
__global__ void combine2(const float* __restrict__ P, const float* __restrict__ b2,
                         const float* __restrict__ O1u, const float* __restrict__ hx,
                         float* __restrict__ out, int nrows, int row0) {
    int i  = blockIdx.x * 256 + threadIdx.x;
    int ft = blockIdx.y;                       // 0..7
    size_t sl = (size_t)8 * nrows * 8;
    size_t o  = ((size_t)ft * nrows + i) * 8;
    size_t ou = ((size_t)ft * nrows + i) * 8;
    size_t g  = (size_t)(row0 + i) * 64 + ft * 8;
    #pragma unroll
    for (int q = 0; q < 8; q += 4) {
        float4 p0 = *(const float4*)(P + o + q);
        float4 p1 = *(const float4*)(P + sl + o + q);
        float4 p2 = *(const float4*)(P + 2 * sl + o + q);
        float4 bb = *(const float4*)(b2 + ft * 8 + q);
        float4 u  = *(const float4*)(O1u + ou + q);
        float4 h  = *(const float4*)(hx + g + q);
        float4 r;
        float c;
        c = tanhf(p0.x + p1.x + p2.x + bb.x); r.x = u.x * h.x + (1.f - u.x) * c;
        c = tanhf(p0.y + p1.y + p2.y + bb.y); r.y = u.y * h.y + (1.f - u.y) * c;
        c = tanhf(p0.z + p1.z + p2.z + bb.z); r.z = u.z * h.z + (1.f - u.z) * c;
        c = tanhf(p0.w + p1.w + p2.w + bb.w); r.w = u.w * h.w + (1.f - u.w) * c;
        *(float4*)(out + g + q) = r;
    }
}

// ---------------------------------------------------------------------------
extern "C" void kernel_launch(void* const* d_in, const int* in_sizes, int n_in,
                              void* d_out, int out_size, void* d_ws, size_t ws_size,
                              hipStream_t stream) {
    const float* inp = (const float*)d_in[0];
    const float* hx  = (const float*)d_in[1];
    const float* L0  = (const float*)d_in[2];
    const float* L1  = (const float*)d_in[3];
    const float* W1  = (const float*)d_in[4];
    const float* b1  = (const float*)d_in[5];
    const float* W2  = (const float*)d_in[6];
    const float* b2  = (const float*)d_in[7];
    float* out = (float*)d_out;

    char* ws = (char*)d_ws;
    size_t off = 0;
    auto carve = [&](size_t bytes) -> char* {
        off = (off + 255) & ~(size_t)255;
        char* p = ws + off;
        off += bytes;
        return p;
    };
    // fixed region
    int*    dcnt  = (int*)   carve(N_NODES * sizeof(int));
    int*    perm0 = (int*)   carve(N_NODES * sizeof(int));
    int*    perm1 = (int*)   carve(N_NODES * sizeof(int));
    int*    scnt0 = (int*)   carve(N_NODES * sizeof(int));
    int*    scnt1 = (int*)   carve(N_NODES * sizeof(int));
    float2* ell0  = (float2*)carve((size_t)N_NODES * CAP * sizeof(float2));
    float2* ell1  = (float2*)carve((size_t)N_NODES * CAP * sizeof(float2));
    unsigned short* Wh1 = (unsigned short*)carve((size_t)F_IN * NT1 * 2);
    unsigned short* Wl1 = (unsigned short*)carve((size_t)F_IN * NT1 * 2);
    unsigned short* Wh2 = (unsigned short*)carve((size_t)F_IN * NT2 * 2);
    unsigned short* Wl2 = (unsigned short*)carve((size_t)F_IN * NT2 * 2);

    // chunking (power-of-two Bc): Pg1 + O1u + O1r + Pg2
    size_t per_batch = (size_t)N_NODES * (NT1 + 64 + 64 + NT2) * sizeof(float);  // ~4.46 MB
    size_t fixed_end = (off + 255) & ~(size_t)255;
    size_t avail = (ws_size > fixed_end + 4096) ? (ws_size - fixed_end - 4096) : per_batch;
    int maxb = (int)(avail / per_batch);
    int Bc = 1;
    while (Bc * 2 <= maxb && Bc * 2 <= BATCH) Bc *= 2;

    float* Pg1  = (float*)carve((size_t)Bc * N_NODES * NT1 * sizeof(float));
    float* O1u  = (float*)carve((size_t)Bc * N_NODES * 64 * sizeof(float));
    float* O1r  = (float*)carve((size_t)Bc * N_NODES * 64 * sizeof(float));
    float* Pg2  = (float*)carve((size_t)Bc * N_NODES * NT2 * sizeof(float));

    degree_count<<<N_NODES / 4, 256, 0, stream>>>(L0, dcnt);
    sort_perm<<<1, 256, 0, stream>>>(dcnt, perm0);
    ell_build<<<N_NODES / 4, 256, 0, stream>>>(L0, perm0, scnt0, ell0);
    degree_count<<<N_NODES / 4, 256, 0, stream>>>(L1, dcnt);
    sort_perm<<<1, 256, 0, stream>>>(dcnt, perm1);
    ell_build<<<N_NODES / 4, 256, 0, stream>>>(L1, perm1, scnt1, ell1);
    wprep_frag<<<(F_IN * NT1 + 255) / 256, 256, 0, stream>>>(W1, Wh1, Wl1, 128, NT1);
    wprep_frag<<<(F_IN * NT2 + 255) / 256, 256, 0, stream>>>(W2, Wh2, Wl2, 64, NT2);

    for (int b0 = 0; b0 < BATCH; b0 += Bc) {
        int bc = (BATCH - b0 < Bc) ? (BATCH - b0) : Bc;
        int nrows = bc * N_NODES;
        int row0 = b0 * N_NODES;

        // ---- gconv1 ----
        gemm_proj<NT1 / 16, 0><<<nrows / 64, 128, 0, stream>>>(
            inp, hx, nullptr, Wh1, Wl1, Pg1, nrows, row0);
        size_t sl1 = (size_t)16 * nrows * 8;
        diffuse2<<<dim3(16, bc, 2), 1024, 0, stream>>>(scnt0, ell0, perm0,
            scnt1, ell1, perm1, Pg1, sl1, nrows);
        combine1<<<dim3(nrows / 256, 16), 256, 0, stream>>>(
            Pg1, b1, hx, O1u, O1r, nrows, row0);

        // ---- gconv2 ----
        gemm_proj<NT2 / 16, 1><<<nrows / 64, 128, 0, stream>>>(
            inp, hx, O1r, Wh2, Wl2, Pg2, nrows, row0);
        size_t sl2 = (size_t)8 * nrows * 8;
        diffuse2<<<dim3(8, bc, 2), 1024, 0, stream>>>(scnt0, ell0, perm0,
            scnt1, ell1, perm1, Pg2, sl2, nrows);
        combine2<<<dim3(nrows / 256, 8), 256, 0, stream>>>(
            Pg2, b2, O1u, hx, out, nrows, row0);
    }
}

// Round 14
// 346.024 us; speedup vs baseline: 1.1970x; 1.1970x over previous
//
#include <hip/hip_runtime.h>
#include <math.h>

#define N_NODES 1024
#define BATCH   64
#define F_IN    128     // D_IN + UNITS (K of the projection GEMM)
#define UNITS   64
#define NUM_M   5
#define CAP     192     // ELL row capacity (max row degree ~55 for this seed)
#define NT1     640     // 5*128 output cols, gconv1
#define NT2     320     // 5*64  output cols, gconv2
#define DSTR    12      // diffusion LDS row stride (floats): empirically best (r9/r12)

typedef __attribute__((ext_vector_type(8))) short short8v;
typedef __attribute__((ext_vector_type(4))) float f32x4;

__device__ __forceinline__ unsigned short bf16_rne(float x) {
    unsigned u = __float_as_uint(x);
    return (unsigned short)((u + 0x7FFFu + ((u >> 16) & 1u)) >> 16);
}

// ---------------- degree count per row (z = operator) -----------------------
__global__ void degree_count(const float* __restrict__ L0, const float* __restrict__ L1,
                             int* __restrict__ dcnt2) {
    const float* L = blockIdx.y ? L1 : L0;
    int row  = blockIdx.x * 4 + (threadIdx.x >> 6);
    int lane = threadIdx.x & 63;
    const float* Lr = L + (size_t)row * N_NODES;
    int c = 0;
    for (int seg = lane; seg < N_NODES; seg += 64) c += (Lr[seg] != 0.0f);
    #pragma unroll
    for (int o = 1; o < 64; o <<= 1) c += __shfl_xor(c, o);
    if (lane == 0) dcnt2[blockIdx.y * N_NODES + row] = c;
}

// ---------------- counting sort by degree (descending), 1 block/operator ----
__global__ void sort_perm(const int* __restrict__ dcnt2, int* __restrict__ perm2) {
    __shared__ int hist[CAP + 1];
    __shared__ int offs[CAP + 1];
    const int* dcnt = dcnt2 + blockIdx.x * N_NODES;
    int*       perm = perm2 + blockIdx.x * N_NODES;
    int tid = threadIdx.x;
    for (int i = tid; i <= CAP; i += 256) hist[i] = 0;
    __syncthreads();
    for (int r = tid; r < N_NODES; r += 256) {
        int c = dcnt[r]; if (c > CAP) c = CAP;
        atomicAdd(&hist[c], 1);
    }
    __syncthreads();
    if (tid == 0) {
        int s = 0;
        for (int c = CAP; c >= 0; --c) { offs[c] = s; s += hist[c]; }
    }
    __syncthreads();
    for (int r = tid; r < N_NODES; r += 256) {
        int c = dcnt[r]; if (c > CAP) c = CAP;
        int pos = atomicAdd(&offs[c], 1);
        perm[pos] = r;
    }
}

// ---------------- ELL build in sorted row order (z = operator) --------------
__global__ void ell_build(const float* __restrict__ L0, const float* __restrict__ L1,
                          const int* __restrict__ perm2,
                          int* __restrict__ scnt2, float2* __restrict__ ell2) {
    const int z = blockIdx.y;
    const float* L = z ? L1 : L0;
    int* scnt = scnt2 + z * N_NODES;
    float2* ell = ell2 + (size_t)z * N_NODES * CAP;
    int p    = blockIdx.x * 4 + (threadIdx.x >> 6);
    int lane = threadIdx.x & 63;
    int row  = perm2[z * N_NODES + p];
    const float* Lr = L + (size_t)row * N_NODES;
    int base = 0;
    for (int seg = 0; seg < N_NODES; seg += 64) {
        float v = Lr[seg + lane];
        bool nz = (v != 0.0f);
        unsigned long long bal = __ballot(nz);
        int off = __popcll(bal & ((1ull << lane) - 1ull));
        if (nz) {
            int idx = base + off;
            if (idx < CAP) ell[(size_t)idx * N_NODES + p] =
                               make_float2(__int_as_float(seg + lane), v);
        }
        base += __popcll(bal);
    }
    if (base > CAP) base = CAP;
    for (int idx = base + lane; idx < CAP; idx += 64)
        ell[(size_t)idx * N_NODES + p] = make_float2(__int_as_float(0), 0.0f);
    if (lane == 0) scnt[p] = (base + 3) & ~3;
}

// ---------------- W' prep: fold + bf16 hi/lo split + MFMA fragment order ----
__global__ void wprep_frag(const float* __restrict__ W, unsigned short* __restrict__ Wh,
                           unsigned short* __restrict__ Wl, int nout, int ntot) {
    int idx = blockIdx.x * blockDim.x + threadIdx.x;
    if (idx >= F_IN * ntot) return;
    int jg = idx % ntot, k = idx / ntot;
    int m = jg / nout, j = jg % nout;
    const float* Wk = W + (size_t)(k * NUM_M) * nout;
    float v;
    if (m == 0)      v = Wk[0 * nout + j] - Wk[3 * nout + j] - Wk[4 * nout + j];
    else if (m == 3) v = 2.0f * Wk[3 * nout + j];
    else if (m == 4) v = 2.0f * Wk[4 * nout + j];
    else             v = Wk[(size_t)m * nout + j];
    unsigned short h = bf16_rne(v);
    float hf = __uint_as_float((unsigned)h << 16);
    unsigned short lo = bf16_rne(v - hf);
    size_t fi = ((((size_t)(jg >> 4) * 4 + (k >> 5)) * 64) + ((k >> 3) & 3) * 16 + (jg & 15)) * 8 + (k & 7);
    Wh[fi] = h; Wl[fi] = lo;
}

// ---------------- MFMA projection v7: fp32 A loads, in-reg split, zero-LDS --
// P^T = W'^T @ xin^T (W frag as MFMA A-operand, X frag as B-operand).
template <int NCG, int RMUL>
__global__ __launch_bounds__(128, 3) void gemm_proj(
        const float* __restrict__ inp, const float* __restrict__ hx,
        const float* __restrict__ rh,
        const unsigned short* __restrict__ Wh, const unsigned short* __restrict__ Wl,
        float* __restrict__ P, int nrows, int row0) {
    const int tid = threadIdx.x;
    const int lane = tid & 63, w = tid >> 6;          // 2 waves/block
    const int l15 = lane & 15, l4 = lane >> 4;
    const int nbase = blockIdx.x * 64 + w * 32;

    short8v ah[2][4], al[2][4];                        // X frags, hoisted
    #pragma unroll
    for (int i = 0; i < 2; ++i)
        #pragma unroll
        for (int s = 0; s < 4; ++s) {
            int row_l = nbase + i * 16 + l15;
            int kg8 = s * 4 + l4;
            size_t g = (size_t)(row0 + row_l);
            float x[8];
            if (kg8 < 8) {
                *(float4*)&x[0] = *(const float4*)(inp + g * 64 + kg8 * 8);
                *(float4*)&x[4] = *(const float4*)(inp + g * 64 + kg8 * 8 + 4);
            } else if (RMUL) {
                const float* rp = rh + ((size_t)(kg8 - 8) * nrows + row_l) * 8;
                *(float4*)&x[0] = *(const float4*)(rp);
                *(float4*)&x[4] = *(const float4*)(rp + 4);
            } else {
                *(float4*)&x[0] = *(const float4*)(hx + g * 64 + (kg8 - 8) * 8);
                *(float4*)&x[4] = *(const float4*)(hx + g * 64 + (kg8 - 8) * 8 + 4);
            }
            #pragma unroll
            for (int e = 0; e < 8; ++e) {
                unsigned short h = bf16_rne(x[e]);
                ah[i][s][e] = (short)h;
                al[i][s][e] = (short)bf16_rne(x[e] - __uint_as_float((unsigned)h << 16));
            }
        }

    const int trow = l4 >> 1, toff = (l4 & 1) * 4;
    #pragma unroll 1
    for (int cg = 0; cg < NCG; ++cg) {
        f32x4 acc[2];
        acc[0] = (f32x4){0.f, 0.f, 0.f, 0.f};
        acc[1] = (f32x4){0.f, 0.f, 0.f, 0.f};
        #pragma unroll
        for (int s = 0; s < 4; ++s) {
            size_t o = (((size_t)cg * 4 + s) * 64 + lane) * 8;
            short8v bh = *(const short8v*)(Wh + o);
            short8v bl = *(const short8v*)(Wl + o);
            #pragma unroll
            for (int i = 0; i < 2; ++i) {
                acc[i] = __builtin_amdgcn_mfma_f32_16x16x32_bf16(bh, al[i][s], acc[i], 0, 0, 0);
                acc[i] = __builtin_amdgcn_mfma_f32_16x16x32_bf16(bl, ah[i][s], acc[i], 0, 0, 0);
                acc[i] = __builtin_amdgcn_mfma_f32_16x16x32_bf16(bh, ah[i][s], acc[i], 0, 0, 0);
            }
        }
        #pragma unroll
        for (int i = 0; i < 2; ++i) {
            float4 v = make_float4(acc[i][0], acc[i][1], acc[i][2], acc[i][3]);
            *(float4*)(P + ((size_t)(cg * 2 + trow) * nrows + (nbase + i * 16 + l15)) * 8 + toff) = v;
        }
    }
}

// ---------------- gather: 4 consecutive sorted rows/thread, j-pair ILP ------
__device__ __forceinline__ void gather2x4(
        const float2* __restrict__ ell, const float* __restrict__ ldsX,
        int tid, int nmax, float4 acc[4][2]) {
    #pragma unroll
    for (int k = 0; k < 4; ++k) {
        acc[k][0] = make_float4(0.f, 0.f, 0.f, 0.f);
        acc[k][1] = make_float4(0.f, 0.f, 0.f, 0.f);
    }
    for (int j = 0; j < nmax; j += 2) {
        const float* e0 = (const float*)(ell + (size_t)j * N_NODES) + (size_t)tid * 8;
        const float* e1 = (const float*)(ell + (size_t)(j + 1) * N_NODES) + (size_t)tid * 8;
        float4 q00 = *(const float4*)e0, q01 = *(const float4*)(e0 + 4);
        float4 q10 = *(const float4*)e1, q11 = *(const float4*)(e1 + 4);
        float cf[2][4], wv[2][4];
        cf[0][0] = q00.x; wv[0][0] = q00.y; cf[0][1] = q00.z; wv[0][1] = q00.w;
        cf[0][2] = q01.x; wv[0][2] = q01.y; cf[0][3] = q01.z; wv[0][3] = q01.w;
        cf[1][0] = q10.x; wv[1][0] = q10.y; cf[1][1] = q10.z; wv[1][1] = q10.w;
        cf[1][2] = q11.x; wv[1][2] = q11.y; cf[1][3] = q11.z; wv[1][3] = q11.w;
        #pragma unroll
        for (int u = 0; u < 2; ++u)
            #pragma unroll
            for (int k = 0; k < 4; ++k) {
                int c = __float_as_int(cf[u][k]);
                float w = wv[u][k];
                const float* xp = ldsX + (size_t)c * DSTR;
                float4 x0 = *(const float4*)xp;
                float4 x1 = *(const float4*)(xp + 4);
                acc[k][0].x += w * x0.x; acc[k][0].y += w * x0.y;
                acc[k][0].z += w * x0.z; acc[k][0].w += w * x0.w;
                acc[k][1].x += w * x1.x; acc[k][1].y += w * x1.y;
                acc[k][1].z += w * x1.z; acc[k][1].w += w * x1.w;
            }
    }
}

// ---------------- diffuse2: ntpb tiles per block (tail-free grids) ----------
// z=0: P1 += L0@P3 then P1 = L0@P1 ; z=1: P2 += L1@P4 then P2 = L1@P2.
__global__ __launch_bounds__(256, 3) void diffuse2(
        const int* __restrict__ scnt2, const float2* __restrict__ ell2,
        const int* __restrict__ perm2,
        float* __restrict__ P, size_t sl, int nrows, int ntpb) {
    __shared__ float ldsX[N_NODES * DSTR];   // 48 KB
    const int tid = threadIdx.x;
    const int z = blockIdx.z;
    const int*    scnt = scnt2 + z * N_NODES;
    const float2* ell  = ell2 + (size_t)z * N_NODES * CAP;
    const int*    perm = perm2 + z * N_NODES;
    const float*  src  = P + (size_t)(z ? 4 : 3) * sl;
    float*        dst  = P + (size_t)(z ? 2 : 1) * sl;   // also the add source

    int4 pr = *(const int4*)(perm + tid * 4);
    int4 cn = *(const int4*)(scnt + tid * 4);
    int orow[4] = {pr.x, pr.y, pr.z, pr.w};
    int nn4 = max(max(cn.x, cn.y), max(cn.z, cn.w));

    #pragma unroll 1
    for (int t = 0; t < ntpb; ++t) {
        const int ft = blockIdx.x * ntpb + t;
        const size_t base = ((size_t)ft * nrows + (size_t)blockIdx.y * N_NODES) * 8;
        if (t) __syncthreads();               // prior item's out-store reads done
        for (int v = tid; v < 2048; v += 256) {
            float4 d = *(const float4*)(src + base + v * 4);
            *(float4*)(ldsX + (v >> 1) * DSTR + (v & 1) * 4) = d;
        }
        __syncthreads();

        float4 T[4][2];
        gather2x4(ell, ldsX, tid, nn4, T);
        __syncthreads();                      // all pass-1 reads complete
        #pragma unroll
        for (int k = 0; k < 4; ++k) {
            const float* ap = dst + base + (size_t)orow[k] * 8;
            float4 a0 = *(const float4*)ap, a1 = *(const float4*)(ap + 4);
            T[k][0].x += a0.x; T[k][0].y += a0.y; T[k][0].z += a0.z; T[k][0].w += a0.w;
            T[k][1].x += a1.x; T[k][1].y += a1.y; T[k][1].z += a1.z; T[k][1].w += a1.w;
            *(float4*)(ldsX + (size_t)orow[k] * DSTR)     = T[k][0];
            *(float4*)(ldsX + (size_t)orow[k] * DSTR + 4) = T[k][1];
        }
        __syncthreads();
        float4 S[4][2];
        gather2x4(ell, ldsX, tid, nn4, S);
        __syncthreads();
        #pragma unroll
        for (int k = 0; k < 4; ++k) {
            *(float4*)(ldsX + (size_t)orow[k] * DSTR)     = S[k][0];
            *(float4*)(ldsX + (size_t)orow[k] * DSTR + 4) = S[k][1];
        }
        __syncthreads();
        for (int v = tid; v < 2048; v += 256)
            *(float4*)(dst + base + v * 4) = *(const float4*)(ldsX + (v >> 1) * DSTR + (v & 1) * 4);
    }
}

// ---------------- combine1 (fused): u tiles + fp32 r*hx tiles ---------------
__global__ void combine1(const float* __restrict__ P, const float* __restrict__ b1,
                         const float* __restrict__ hx,
                         float* __restrict__ O1u, float* __restrict__ O1r,
                         int nrows, int row0) {
    int i  = blockIdx.x * 256 + threadIdx.x;
    int ft = blockIdx.y;
    size_t sl = (size_t)16 * nrows * 8;
    size_t o  = ((size_t)ft * nrows + i) * 8;
    float z[8];
    #pragma unroll
    for (int q = 0; q < 8; q += 4) {
        float4 p0 = *(const float4*)(P + o + q);
        float4 p1 = *(const float4*)(P + sl + o + q);
        float4 p2 = *(const float4*)(P + 2 * sl + o + q);
        float4 bb = *(const float4*)(b1 + ft * 8 + q);
        z[q + 0] = 1.f / (1.f + expf(-(p0.x + p1.x + p2.x + bb.x)));
        z[q + 1] = 1.f / (1.f + expf(-(p0.y + p1.y + p2.y + bb.y)));
        z[q + 2] = 1.f / (1.f + expf(-(p0.z + p1.z + p2.z + bb.z)));
        z[q + 3] = 1.f / (1.f + expf(-(p0.w + p1.w + p2.w + bb.w)));
    }
    if (ft >= 8) {
        size_t ou = ((size_t)(ft - 8) * nrows + i) * 8;
        *(float4*)(O1u + ou)     = make_float4(z[0], z[1], z[2], z[3]);
        *(float4*)(O1u + ou + 4) = make_float4(z[4], z[5], z[6], z[7]);
    } else {
        size_t g = (size_t)(row0 + i) * 64 + ft * 8;
        float4 h0 = *(const float4*)(hx + g), h1 = *(const float4*)(hx + g + 4);
        size_t orr = ((size_t)ft * nrows + i) * 8;
        *(float4*)(O1r + orr)     = make_float4(z[0] * h0.x, z[1] * h0.y, z[2] * h0.z, z[3] * h0.w);
        *(float4*)(O1r + orr + 4) = make_float4(z[4] * h1.x, z[5] * h1.y, z[6] * h1.z, z[7] * h1.w);
    }
}

// ---------------- combine2: out = u*hx + (1-u)*tanh(P0+S1+S2+b2) -----------
__global__ void combine2(const float* __restrict__ P, const float* __restrict__ b2,
                         const float* __restrict__ O1u, const float* __restrict__ hx,
                         float* __restrict__ out, int nrows, int row0) {
    int i  = blockIdx.x * 256 + threadIdx.x;
    int ft = blockIdx.y;                       // 0..7
    size_t sl = (size_t)8 * nrows * 8;
    size_t o  = ((size_t)ft * nrows + i) * 8;
    size_t ou = ((size_t)ft * nrows + i) * 8;
    size_t g  = (size_t)(row0 + i) * 64 + ft * 8;
    #pragma unroll
    for (int q = 0; q < 8; q += 4) {
        float4 p0 = *(const float4*)(P + o + q);
        float4 p1 = *(const float4*)(P + sl + o + q);
        float4 p2 = *(const float4*)(P + 2 * sl + o + q);
        float4 bb = *(const float4*)(b2 + ft * 8 + q);
        float4 u  = *(const float4*)(O1u + ou + q);
        float4 h  = *(const float4*)(hx + g + q);
        float4 r;
        float c;
        c = tanhf(p0.x + p1.x + p2.x + bb.x); r.x = u.x * h.x + (1.f - u.x) * c;
        c = tanhf(p0.y + p1.y + p2.y + bb.y); r.y = u.y * h.y + (1.f - u.y) * c;
        c = tanhf(p0.z + p1.z + p2.z + bb.z); r.z = u.z * h.z + (1.f - u.z) * c;
        c = tanhf(p0.w + p1.w + p2.w + bb.w); r.w = u.w * h.w + (1.f - u.w) * c;
        *(float4*)(out + g + q) = r;
    }
}

// ---------------------------------------------------------------------------
extern "C" void kernel_launch(void* const* d_in, const int* in_sizes, int n_in,
                              void* d_out, int out_size, void* d_ws, size_t ws_size,
                              hipStream_t stream) {
    const float* inp = (const float*)d_in[0];
    const float* hx  = (const float*)d_in[1];
    const float* L0  = (const float*)d_in[2];
    const float* L1  = (const float*)d_in[3];
    const float* W1  = (const float*)d_in[4];
    const float* b1  = (const float*)d_in[5];
    const float* W2  = (const float*)d_in[6];
    const float* b2  = (const float*)d_in[7];
    float* out = (float*)d_out;

    char* ws = (char*)d_ws;
    size_t off = 0;
    auto carve = [&](size_t bytes) -> char* {
        off = (off + 255) & ~(size_t)255;
        char* p = ws + off;
        off += bytes;
        return p;
    };
    // fixed region (both operators packed: [2][...])
    int*    dcnt2 = (int*)   carve(2 * N_NODES * sizeof(int));
    int*    perm2 = (int*)   carve(2 * N_NODES * sizeof(int));
    int*    scnt2 = (int*)   carve(2 * N_NODES * sizeof(int));
    float2* ell2  = (float2*)carve((size_t)2 * N_NODES * CAP * sizeof(float2));
    unsigned short* Wh1 = (unsigned short*)carve((size_t)F_IN * NT1 * 2);
    unsigned short* Wl1 = (unsigned short*)carve((size_t)F_IN * NT1 * 2);
    unsigned short* Wh2 = (unsigned short*)carve((size_t)F_IN * NT2 * 2);
    unsigned short* Wl2 = (unsigned short*)carve((size_t)F_IN * NT2 * 2);

    // chunking: Pg1 extended to 88 tiles (Pg2 aliases tiles 48-87) + O1u + O1r
    size_t per_batch = (size_t)N_NODES * (88 * 8 + 64 + 64) * sizeof(float);   // ~3.41 MB
    size_t fixed_end = (off + 255) & ~(size_t)255;
    size_t avail = (ws_size > fixed_end + 4096) ? (ws_size - fixed_end - 4096) : per_batch;
    int maxb = (int)(avail / per_batch);
    int Bc = 1;
    while (Bc * 2 <= maxb && Bc * 2 <= BATCH) Bc *= 2;

    float* Pg1  = (float*)carve((size_t)Bc * N_NODES * 88 * 8 * sizeof(float));
    float* O1u  = (float*)carve((size_t)Bc * N_NODES * 64 * sizeof(float));
    float* O1r  = (float*)carve((size_t)Bc * N_NODES * 64 * sizeof(float));

    degree_count<<<dim3(N_NODES / 4, 2), 256, 0, stream>>>(L0, L1, dcnt2);
    sort_perm<<<2, 256, 0, stream>>>(dcnt2, perm2);
    ell_build<<<dim3(N_NODES / 4, 2), 256, 0, stream>>>(L0, L1, perm2, scnt2, ell2);
    wprep_frag<<<(F_IN * NT1 + 255) / 256, 256, 0, stream>>>(W1, Wh1, Wl1, 128, NT1);
    wprep_frag<<<(F_IN * NT2 + 255) / 256, 256, 0, stream>>>(W2, Wh2, Wl2, 64, NT2);

    for (int b0 = 0; b0 < BATCH; b0 += Bc) {
        int bc = (BATCH - b0 < Bc) ? (BATCH - b0) : Bc;
        int nrows = bc * N_NODES;
        int row0 = b0 * N_NODES;
        float* Pg2 = Pg1 + (size_t)48 * nrows * 8;   // alias: tiles 48-87 of Pg1

        // tail-free tiles-per-block: target <= 512 blocks per diffuse dispatch
        int ntpb1 = 1; while ((16 / ntpb1) * bc * 2 > 512 && ntpb1 < 16) ntpb1 *= 2;
        int ntpb2 = 1; while ((8  / ntpb2) * bc * 2 > 512 && ntpb2 < 8)  ntpb2 *= 2;

        // ---- gconv1 ----
        gemm_proj<NT1 / 16, 0><<<nrows / 64, 128, 0, stream>>>(
            inp, hx, nullptr, Wh1, Wl1, Pg1, nrows, row0);
        size_t sl1 = (size_t)16 * nrows * 8;
        diffuse2<<<dim3(16 / ntpb1, bc, 2), 256, 0, stream>>>(
            scnt2, ell2, perm2, Pg1, sl1, nrows, ntpb1);
        combine1<<<dim3(nrows / 256, 16), 256, 0, stream>>>(
            Pg1, b1, hx, O1u, O1r, nrows, row0);

        // ---- gconv2 ----
        gemm_proj<NT2 / 16, 1><<<nrows / 64, 128, 0, stream>>>(
            inp, hx, O1r, Wh2, Wl2, Pg2, nrows, row0);
        size_t sl2 = (size_t)8 * nrows * 8;
        diffuse2<<<dim3(8 / ntpb2, bc, 2), 256, 0, stream>>>(
            scnt2, ell2, perm2, Pg2, sl2, nrows, ntpb2);
        combine2<<<dim3(nrows / 256, 8), 256, 0, stream>>>(
            Pg2, b2, O1u, hx, out, nrows, row0);
    }
}